// Round 4
// baseline (156.923 us; speedup 1.0000x reference)
//
#include <hip/hip_runtime.h>
#include <math.h>

// JointAttentionMemoryBank via fp16 MFMA.  out = W @ softmax(W^T x / sqrt(D))
//   B=16 N=4096 D=128 M=1536.  fp32 in/out.
// R10: register-fused P (permlane32_swap), m-partitioned phase 2.
//  R9 post-mortem: 8 waves/CU = latency-bound, pipes sum not overlap. Need
//  16 waves/CU (4/SIMD, <=128 VGPR) AND low operand traffic. This round:
//  - Wave (wm,u) computes S-tile (mt=2q+wm) x (nt=u) -> P stays IN REGISTERS:
//    phase-1 C layout (n=l31, m=r+8g+4hi) == phase-2 B layout (n=l31, k=8hi+j)
//    up to a lane-pair hi/lo exchange: 2x v_permlane32_swap_b32 per kstep
//    (T12 pattern). Pbuf deleted; no p1->p2 barrier (register dataflow).
//  - Phase 2 m-partitioned: c[4 dt] f32 partials over wave's own m; cross-wm
//    reduction once at kernel end through the then-free staging LDS.
//  - WT and WD staged read-once/block via global_load_lds(16B), double-buffered
//    16KB slices (wd reordered km-major so session slices are contiguous).
//    All LDS reads contiguous-1KB b128 -> zero bank conflicts by construction.
//  - bx (32n x 128d fp16) in 32 VGPRs, loaded once. One __syncthreads/session.
// LDS 64.5KB, target <=128 VGPR -> 2 blocks/CU, 16 waves/CU.
// exp2-folded scale in wt. No-max softmax, P unnormalized fp16, fp32 epilogue.

#define Bdim 16
#define Ndim 4096
#define Ddim 128
#define Mdim 1536
#define NT 128              // rows (n) per block
#define NTHREADS 512        // 8 waves
#define NSESS 24            // m-sessions (64 m each)
#define NFRAG 24576         // fragments per W array = D*M/8

typedef __attribute__((ext_vector_type(8)))  _Float16 f16x8;   // 4 VGPRs
typedef __attribute__((ext_vector_type(16))) float    f32x16;  // 32x32 MFMA C/D

union H2 { _Float16 h[2]; unsigned u; };
union F8 { unsigned u[4]; f16x8 v; };

// ---- prep: W (D,M) fp32 -> fragment-ordered fp16 arrays (32x32x16 form) ----
// wt (phase-1 A = W^T, pre-scaled log2e/sqrt(D)):
//   frag f = (mt32*8 + ks)*64 + l ; m = mt32*32 + (l&31), d = ks*16 + (l>>5)*8 + j
//   (session slice q = frags [q*16..(q+1)*16) = contiguous 16KB)
// wd (phase-2 A = W), km-major for contiguous session slices:
//   frag f = (km*4 + dt)*64 + l ; d = dt*32 + (l&31), m = km*16 + (l>>5)*8 + j
__global__ void jamb_prep(const float* __restrict__ w,
                          _Float16* __restrict__ wt,
                          _Float16* __restrict__ wd) {
    const int tid = blockIdx.x * 256 + threadIdx.x;   // [0, 2*NFRAG)
    const float SC = 0.12751742957f;                  // log2(e)/sqrt(128)
    if (tid < NFRAG) {                                // wt (column gather)
        const int f    = tid;
        const int l    = f & 63;
        const int fs   = f >> 6;
        const int ks   = fs & 7;          // 0..7
        const int mt   = fs >> 3;         // 0..47
        const int m    = mt * 32 + (l & 31);
        const int d0   = ks * 16 + (l >> 5) * 8;
        f16x8 pk;
        #pragma unroll
        for (int j = 0; j < 8; ++j)
            pk[j] = (_Float16)(w[(size_t)(d0 + j) * Mdim + m] * SC);
        *(f16x8*)&wt[(size_t)f * 8] = pk;
    } else {                                          // wd (row-contiguous)
        const int f    = tid - NFRAG;
        const int l    = f & 63;
        const int fs   = f >> 6;          // 0..383
        const int dt   = fs & 3;          // 0..3
        const int km   = fs >> 2;         // 0..95
        const int d    = dt * 32 + (l & 31);
        const int m0   = km * 16 + (l >> 5) * 8;
        const float* src = w + (size_t)d * Mdim + m0;
        const float4 v0 = *(const float4*)src;
        const float4 v1 = *(const float4*)(src + 4);
        f16x8 pk;
        pk[0] = (_Float16)v0.x; pk[1] = (_Float16)v0.y;
        pk[2] = (_Float16)v0.z; pk[3] = (_Float16)v0.w;
        pk[4] = (_Float16)v1.x; pk[5] = (_Float16)v1.y;
        pk[6] = (_Float16)v1.z; pk[7] = (_Float16)v1.w;
        *(f16x8*)&wd[(size_t)f * 8] = pk;
    }
}

static __device__ __forceinline__ void glds16(const void* g, void* l) {
    __builtin_amdgcn_global_load_lds(
        (const __attribute__((address_space(1))) unsigned*)g,
        (__attribute__((address_space(3))) unsigned*)l, 16, 0, 0);
}

__global__ __launch_bounds__(NTHREADS, 4)
void jamb_mfma_kernel(const float* __restrict__ x,
                      const _Float16* __restrict__ wt,
                      const _Float16* __restrict__ wd,
                      float* __restrict__ out) {
    // [0,16K)x2: WT slice dbuf; [32K,48K)x2: WD slice dbuf; reused for c-reduce.
    __shared__ __align__(16) unsigned char smem[65536];
    __shared__ float sred[4][32];

    const int t   = threadIdx.x;
    const int w   = t >> 6;         // wave 0..7
    const int l   = t & 63;
    const int l31 = l & 31;
    const int hi  = l >> 5;
    const int wm  = w >> 2;         // m-half: this wave's session m-tile = 2q+wm
    const int u   = w & 3;          // n-quarter (nt = u), fixed all kernel

    const int blk   = blockIdx.x;
    const int b     = blk >> 5;             // 32 blocks per batch (4096/128)
    const int nbase = (blk & 31) * NT;

    // ---- x B-fragments for this wave's fixed 32-n quarter: 8 frags = 32 VGPR ----
    f16x8 bx[8];
    {
        const float* xr = x + (size_t)(b * Ndim + nbase + u * 32 + l31) * Ddim;
        #pragma unroll
        for (int ks = 0; ks < 8; ++ks) {
            const float* s = xr + ks * 16 + hi * 8;
            const float4 v0 = *(const float4*)s;
            const float4 v1 = *(const float4*)(s + 4);
            f16x8 pk;
            pk[0] = (_Float16)v0.x; pk[1] = (_Float16)v0.y;
            pk[2] = (_Float16)v0.z; pk[3] = (_Float16)v0.w;
            pk[4] = (_Float16)v1.x; pk[5] = (_Float16)v1.y;
            pk[6] = (_Float16)v1.z; pk[7] = (_Float16)v1.w;
            bx[ks] = pk;
        }
    }

    const char* wtc = (const char*)wt;
    const char* wdc = (const char*)wd;
    const int lane16 = l * 16;
    const int chunk  = w * 2048;    // per-wave staging chunk within 16KB slice

    // stage session q's WT+WD 16KB slices into buffer (q&1); 4 async calls/wave
    auto stage = [&](int q) {
        const int bs = (q & 1) * 16384;
        const int gq = q * 16384;
        glds16(wtc + gq + chunk + 0    + lane16, smem + bs + chunk + 0);
        glds16(wtc + gq + chunk + 1024 + lane16, smem + bs + chunk + 1024);
        glds16(wdc + gq + chunk + 0    + lane16, smem + 32768 + bs + chunk + 0);
        glds16(wdc + gq + chunk + 1024 + lane16, smem + 32768 + bs + chunk + 1024);
    };

    float ssum = 0.f;               // softmax partial: n = nbase+u*32+l31, own m's
    f32x16 c[4];                    // phase-2 partials: dt 0..3, own m only
    #pragma unroll
    for (int dt = 0; dt < 4; ++dt) c[dt] = (f32x16)(0.f);

    stage(0);
    __syncthreads();                // drains own vmcnt -> slice 0 visible to all

    #pragma unroll 1
    for (int q = 0; q < NSESS; ++q) {
        if (q + 1 < NSESS) stage(q + 1);     // async into other buffer, overlaps compute
        const _Float16* WTl = (const _Float16*)(smem + (q & 1) * 16384);
        const _Float16* WDl = (const _Float16*)(smem + 32768 + (q & 1) * 16384);

        // ---- phase 1: S-tile (mt=2q+wm) x (nt=u); exp; pack to registers ----
        f32x16 acc = (f32x16)(0.f);
        #pragma unroll
        for (int ks = 0; ks < 8; ++ks) {
            const f16x8 fh = *(const f16x8*)(WTl + ((wm * 8 + ks) * 64 + l) * 8);
            acc = __builtin_amdgcn_mfma_f32_32x32x16_f16(fh, bx[ks], acc, 0, 0, 0);
        }
        unsigned Wg[4][2];          // per g: 2 packed f16x2 words (m = 8g+4hi+0..3)
        #pragma unroll
        for (int g = 0; g < 4; ++g) {
            const float e0 = exp2f(acc[4 * g + 0]);   // wt pre-scaled by log2e
            const float e1 = exp2f(acc[4 * g + 1]);
            const float e2 = exp2f(acc[4 * g + 2]);
            const float e3 = exp2f(acc[4 * g + 3]);
            ssum += (e0 + e1) + (e2 + e3);
            H2 pa; pa.h[0] = (_Float16)e0; pa.h[1] = (_Float16)e1;
            H2 pb; pb.h[0] = (_Float16)e2; pb.h[1] = (_Float16)e3;
            Wg[g][0] = pa.u; Wg[g][1] = pb.u;
        }
        // C->B relayout: B-frag[k2] j0..3 from hi_src=0 of g=2k2+hi_self,
        // j4..7 from hi_src=1 of same g. One swap (D.hi <-> S.lo) per word pair
        // yields both halves: D'=[D_lo,S_lo] (j0..1), S'=[D_hi,S_hi] (j4..5).
        F8 pf[2];
        #pragma unroll
        for (int k2 = 0; k2 < 2; ++k2) {
            unsigned a0 = Wg[2 * k2][0], b0 = Wg[2 * k2 + 1][0];
            unsigned a1 = Wg[2 * k2][1], b1 = Wg[2 * k2 + 1][1];
            asm volatile("v_permlane32_swap_b32 %0, %1" : "+v"(a0), "+v"(b0));
            asm volatile("v_permlane32_swap_b32 %0, %1" : "+v"(a1), "+v"(b1));
            pf[k2].u[0] = a0; pf[k2].u[1] = a1;
            pf[k2].u[2] = b0; pf[k2].u[3] = b1;
        }

        // ---- phase 2: c[dt] += W[dt, own m-slice] * P (register B-frags) ----
        #pragma unroll
        for (int k2 = 0; k2 < 2; ++k2) {
            const int kk = 2 * wm + k2;       // km local to session slice
            #pragma unroll
            for (int dt = 0; dt < 4; ++dt) {
                const f16x8 a = *(const f16x8*)(WDl + ((kk * 4 + dt) * 64 + l) * 8);
                c[dt] = __builtin_amdgcn_mfma_f32_32x32x16_f16(a, pf[k2].v, c[dt], 0, 0, 0);
            }
        }
        __syncthreads();    // all reads of buf q&1 done; own stage(q+1) landed
    }

    // ---- epilogue: fold hi halves; cross-wm reduce via (now free) staging LDS ----
    ssum += __shfl_xor(ssum, 32, 64);
    if (wm == 1) {
        if (hi == 0) sred[u][l31] = ssum;
        float* cx = (float*)smem + u * 4096;    // 16KB per u-quarter
        #pragma unroll
        for (int dt = 0; dt < 4; ++dt) {
            #pragma unroll
            for (int g = 0; g < 4; ++g) {
                float4 v;
                v.x = c[dt][4 * g + 0]; v.y = c[dt][4 * g + 1];
                v.z = c[dt][4 * g + 2]; v.w = c[dt][4 * g + 3];
                *(float4*)(cx + ((dt * 4 + g) * 64 + l) * 4) = v;
            }
        }
    }
    __syncthreads();
    if (wm == 0) {
        const float inv = 1.f / (ssum + sred[u][l31]);
        const float* cx = (const float*)smem + u * 4096;
        float* ob = out + (size_t)(b * Ndim + nbase + u * 32 + l31) * Ddim;
        #pragma unroll
        for (int dt = 0; dt < 4; ++dt) {
            #pragma unroll
            for (int g = 0; g < 4; ++g) {
                const float4 pc = *(const float4*)(cx + ((dt * 4 + g) * 64 + l) * 4);
                float4 o;
                o.x = (c[dt][4 * g + 0] + pc.x) * inv;
                o.y = (c[dt][4 * g + 1] + pc.y) * inv;
                o.z = (c[dt][4 * g + 2] + pc.z) * inv;
                o.w = (c[dt][4 * g + 3] + pc.w) * inv;
                *(float4*)(ob + dt * 32 + g * 8 + hi * 4) = o;
            }
        }
    }
}

extern "C" void kernel_launch(void* const* d_in, const int* in_sizes, int n_in,
                              void* d_out, int out_size, void* d_ws, size_t ws_size,
                              hipStream_t stream) {
    const float* x = (const float*)d_in[0];   // (B,N,D)
    const float* w = (const float*)d_in[1];   // (1,D,M)
    float* out = (float*)d_out;
    (void)in_sizes; (void)n_in; (void)out_size; (void)ws_size;

    _Float16* wt = (_Float16*)d_ws;           // 384 KB
    _Float16* wd = wt + Ddim * Mdim;          // 384 KB

    jamb_prep<<<dim3((2 * NFRAG) / 256), dim3(256), 0, stream>>>(w, wt, wd);  // 192 blocks
    jamb_mfma_kernel<<<dim3((Bdim * Ndim) / NT), dim3(NTHREADS), 0, stream>>>(x, wt, wd, out);
}